// Round 1
// baseline (551.730 us; speedup 1.0000x reference)
//
#include <hip/hip_runtime.h>
#include <hip/hip_bf16.h>
#include <cstdint>
#include <cstddef>

#define BB 2
#define SS 2048
#define HH 2048
#define NHH 16
#define DHH 128

using f32x4  = __attribute__((ext_vector_type(4))) float;
using bf16x8 = __attribute__((ext_vector_type(8))) __bf16;
using bf16x4 = __attribute__((ext_vector_type(4))) __bf16;
using bfloat = __bf16;

__device__ inline void gload_lds16(const void* g, void* l) {
    __builtin_amdgcn_global_load_lds(
        (const __attribute__((address_space(1))) void*)g,
        (__attribute__((address_space(3))) void*)l, 16, 0, 0);
}

__device__ inline f32x4 mfma16(bf16x8 a, bf16x8 b, f32x4 c) {
    return __builtin_amdgcn_mfma_f32_16x16x32_bf16(a, b, c, 0, 0, 0);
}

// ---------------- fp32 -> bf16 conversion ----------------
__global__ void cvt_bf16(const float* __restrict__ in, bfloat* __restrict__ out, int n4) {
    int i = blockIdx.x * blockDim.x + threadIdx.x;
    if (i >= n4) return;
    float4 v = reinterpret_cast<const float4*>(in)[i];
    bf16x4 o;
    o[0] = (bfloat)v.x; o[1] = (bfloat)v.y; o[2] = (bfloat)v.z; o[3] = (bfloat)v.w;
    reinterpret_cast<bf16x4*>(out)[i] = o;
}

// ---------------- RoPE tables (S x 64) ----------------
__global__ void rope_table(float* __restrict__ cosT, float* __restrict__ sinT) {
    int i = blockIdx.x * blockDim.x + threadIdx.x;
    if (i >= SS * 64) return;
    int s = i >> 6, j = i & 63;
    float invf = powf(10000.0f, -(float)j / 64.0f);
    float ang = (float)s * invf;
    cosT[i] = cosf(ang);
    sinT[i] = sinf(ang);
}

// ---------------- RoPE apply in-place ----------------
__global__ void rope_apply(bfloat* __restrict__ X, const float* __restrict__ cosT,
                           const float* __restrict__ sinT) {
    int i = blockIdx.x * blockDim.x + threadIdx.x;
    if (i >= BB * SS * NHH * 64) return;
    int j = i & 63;
    int row = i >> 6;               // (b*S + s)*NH + h
    int s = (row >> 4) & (SS - 1);
    size_t base = (size_t)row * DHH;
    float x1 = (float)X[base + j];
    float x2 = (float)X[base + 64 + j];
    float c = cosT[s * 64 + j], sn = sinT[s * 64 + j];
    X[base + j]      = (bfloat)(x1 * c - x2 * sn);
    X[base + 64 + j] = (bfloat)(x2 * c + x1 * sn);
}

// ---------------- GEMM: C(MxN) = A(MxK) * Bt(NxK)^T + bias ----------------
template <int OUTF32>
__global__ __launch_bounds__(256, 2)
void gemm_bt(const bfloat* __restrict__ A, const bfloat* __restrict__ Bt,
             const float* __restrict__ bias, void* __restrict__ C,
             int M, int N, int K) {
    constexpr int BM = 128, BN = 128, BK = 32;
    __shared__ bfloat As[BM * BK];
    __shared__ bfloat Bs[BN * BK];
    const int t = threadIdx.x, w = t >> 6, l = t & 63;
    const int lr = l & 15, lg = l >> 4;
    const int m0 = blockIdx.x * BM, n0 = blockIdx.y * BN;
    const int wm = (w >> 1) * 64, wn = (w & 1) * 64;
    const int base = (t & ~63) * 8;   // wave-uniform LDS element base

    f32x4 acc[4][4] = {};

    for (int kb = 0; kb < K; kb += BK) {
#pragma unroll
        for (int i = 0; i < 2; i++) {
            int idx = i * 256 + t;
            int r = idx >> 2, k8 = (idx & 3) << 3;
            gload_lds16(A  + (size_t)(m0 + r) * K + kb + k8, As + (i * 2048 + base));
            gload_lds16(Bt + (size_t)(n0 + r) * K + kb + k8, Bs + (i * 2048 + base));
        }
        __syncthreads();
        bf16x8 af[4], bfr[4];
#pragma unroll
        for (int mi = 0; mi < 4; mi++)
            af[mi] = *reinterpret_cast<const bf16x8*>(&As[(wm + mi * 16 + lr) * BK + lg * 8]);
#pragma unroll
        for (int ni = 0; ni < 4; ni++)
            bfr[ni] = *reinterpret_cast<const bf16x8*>(&Bs[(wn + ni * 16 + lr) * BK + lg * 8]);
#pragma unroll
        for (int mi = 0; mi < 4; mi++)
#pragma unroll
            for (int ni = 0; ni < 4; ni++)
                acc[mi][ni] = mfma16(af[mi], bfr[ni], acc[mi][ni]);
        __syncthreads();
    }

#pragma unroll
    for (int mi = 0; mi < 4; mi++) {
        int row = m0 + wm + mi * 16 + lg * 4;
#pragma unroll
        for (int ni = 0; ni < 4; ni++) {
            int col = n0 + wn + ni * 16 + lr;
            float bv = bias[col];
#pragma unroll
            for (int j = 0; j < 4; j++) {
                float v = acc[mi][ni][j] + bv;
                if (OUTF32)
                    ((float*)C)[(size_t)(row + j) * N + col] = v;
                else
                    ((bfloat*)C)[(size_t)(row + j) * N + col] = (bfloat)v;
            }
        }
    }
}

// ---------------- Flash attention (causal) ----------------
// Q,K,V layout: (b, s, h*DH + d).  Block: 64 q-rows, 4 waves (16 rows each).
__global__ __launch_bounds__(256, 2)
void attn_fwd(const bfloat* __restrict__ Q, const bfloat* __restrict__ K,
              const bfloat* __restrict__ V, bfloat* __restrict__ O) {
    constexpr int KVB = 32;
    __shared__ bfloat Ks[KVB][DHH + 8];    // padded to break bank conflicts
    __shared__ bfloat Vt[DHH][KVB + 8];    // transposed V tile
    __shared__ bfloat Pw[4][16][KVB];      // per-wave P staging

    const int t = threadIdx.x, w = t >> 6, l = t & 63;
    const int lr = l & 15, lg = l >> 4;
    const int b = blockIdx.y >> 4, h = blockIdx.y & 15;
    const int qb = blockIdx.x * 64;
    const int q0 = qb + w * 16;
    const size_t bo_ = (size_t)b * SS * HH + (size_t)h * DHH;
    const bfloat* Qp = Q + bo_;
    const bfloat* Kp = K + bo_;
    const bfloat* Vp = V + bo_;

    bf16x8 qf[4];
#pragma unroll
    for (int kt = 0; kt < 4; kt++)
        qf[kt] = *reinterpret_cast<const bf16x8*>(Qp + (size_t)(q0 + lr) * HH + kt * 32 + lg * 8);

    f32x4 o[8] = {};
    float m[4], ls[4];
#pragma unroll
    for (int j = 0; j < 4; j++) { m[j] = -1e30f; ls[j] = 0.f; }
    const float scale = 0.088388347648318447f;   // 1/sqrt(128)

    const int nkv = (qb >> 5) + 2;
    for (int kv = 0; kv < nkv; ++kv) {
        const int kv0 = kv * KVB;
        __syncthreads();   // previous iteration's readers done before restage
#pragma unroll
        for (int i = 0; i < 2; i++) {
            int g = t * 2 + i;            // 0..511
            int r = g >> 4, c8 = (g & 15) * 8;
            bf16x8 kk = *reinterpret_cast<const bf16x8*>(Kp + (size_t)(kv0 + r) * HH + c8);
            *reinterpret_cast<bf16x8*>(&Ks[r][c8]) = kk;
            bf16x8 vv = *reinterpret_cast<const bf16x8*>(Vp + (size_t)(kv0 + r) * HH + c8);
#pragma unroll
            for (int e = 0; e < 8; e++) Vt[c8 + e][r] = vv[e];
        }
        __syncthreads();

        f32x4 s0 = {}, s1 = {};
#pragma unroll
        for (int kt = 0; kt < 4; kt++) {
            bf16x8 k0 = *reinterpret_cast<const bf16x8*>(&Ks[lr][kt * 32 + lg * 8]);
            bf16x8 k1 = *reinterpret_cast<const bf16x8*>(&Ks[16 + lr][kt * 32 + lg * 8]);
            s0 = mfma16(qf[kt], k0, s0);
            s1 = mfma16(qf[kt], k1, s1);
        }

        float p0[4], p1[4], alpha[4];
#pragma unroll
        for (int j = 0; j < 4; j++) {
            int qr = q0 + lg * 4 + j;
            float a = s0[j] * scale, bq_ = s1[j] * scale;
            if (kv0 + lr > qr)      a   = -1e30f;
            if (kv0 + 16 + lr > qr) bq_ = -1e30f;
            float mx = fmaxf(a, bq_);
            mx = fmaxf(mx, __shfl_xor(mx, 1));
            mx = fmaxf(mx, __shfl_xor(mx, 2));
            mx = fmaxf(mx, __shfl_xor(mx, 4));
            mx = fmaxf(mx, __shfl_xor(mx, 8));
            float mn = fmaxf(m[j], mx);
            alpha[j] = __expf(m[j] - mn);
            m[j] = mn;
            p0[j] = __expf(a - mn);
            p1[j] = __expf(bq_ - mn);
            float rs = p0[j] + p1[j];
            rs += __shfl_xor(rs, 1);
            rs += __shfl_xor(rs, 2);
            rs += __shfl_xor(rs, 4);
            rs += __shfl_xor(rs, 8);
            ls[j] = ls[j] * alpha[j] + rs;
        }
#pragma unroll
        for (int nt = 0; nt < 8; nt++)
#pragma unroll
            for (int j = 0; j < 4; j++) o[nt][j] *= alpha[j];

#pragma unroll
        for (int j = 0; j < 4; j++) {
            Pw[w][lg * 4 + j][lr]      = (bfloat)p0[j];
            Pw[w][lg * 4 + j][16 + lr] = (bfloat)p1[j];
        }
        __syncthreads();

        bf16x8 pa = *reinterpret_cast<const bf16x8*>(&Pw[w][lr][lg * 8]);
#pragma unroll
        for (int nt = 0; nt < 8; nt++) {
            bf16x8 vf = *reinterpret_cast<const bf16x8*>(&Vt[nt * 16 + lr][lg * 8]);
            o[nt] = mfma16(pa, vf, o[nt]);
        }
    }

    bfloat* Op = O + bo_;
#pragma unroll
    for (int j = 0; j < 4; j++) {
        float inv = 1.0f / ls[j];
        int row = q0 + lg * 4 + j;
#pragma unroll
        for (int nt = 0; nt < 8; nt++)
            Op[(size_t)row * HH + nt * 16 + lr] = (bfloat)(o[nt][j] * inv);
    }
}

// ---------------- launch ----------------
extern "C" void kernel_launch(void* const* d_in, const int* in_sizes, int n_in,
                              void* d_out, int out_size, void* d_ws, size_t ws_size,
                              hipStream_t stream) {
    (void)in_sizes; (void)n_in; (void)out_size; (void)ws_size;
    const float* hs = (const float*)d_in[0];
    const float* Wq = (const float*)d_in[2];
    const float* bq = (const float*)d_in[3];
    const float* Wk = (const float*)d_in[4];
    const float* bk = (const float*)d_in[5];
    const float* Wv = (const float*)d_in[6];
    const float* bv = (const float*)d_in[7];
    const float* Wo = (const float*)d_in[8];
    const float* bo = (const float*)d_in[9];

    char* ws = (char*)d_ws;
    size_t off = 0;
    auto alloc = [&](size_t bytes) { void* p = ws + off; off += (bytes + 255) & ~(size_t)255; return p; };
    const size_t MK = (size_t)BB * SS * HH;   // 8M elems
    const size_t NK = (size_t)HH * HH;        // 4M elems

    bfloat* Xb  = (bfloat*)alloc(MK * 2);
    bfloat* Wqb = (bfloat*)alloc(NK * 2);
    bfloat* Wkb = (bfloat*)alloc(NK * 2);
    bfloat* Wvb = (bfloat*)alloc(NK * 2);
    bfloat* Wob = (bfloat*)alloc(NK * 2);
    bfloat* Qb  = (bfloat*)alloc(MK * 2);
    bfloat* Kb  = (bfloat*)alloc(MK * 2);
    bfloat* Vb  = (bfloat*)alloc(MK * 2);
    float*  cosT = (float*)alloc((size_t)SS * 64 * 4);
    float*  sinT = (float*)alloc((size_t)SS * 64 * 4);
    bfloat* AOb = Xb;   // reuse: X no longer needed after V GEMM

    cvt_bf16<<<(int)(MK / 4 / 256), 256, 0, stream>>>(hs, Xb, (int)(MK / 4));
    cvt_bf16<<<(int)(NK / 4 / 256), 256, 0, stream>>>(Wq, Wqb, (int)(NK / 4));
    cvt_bf16<<<(int)(NK / 4 / 256), 256, 0, stream>>>(Wk, Wkb, (int)(NK / 4));
    cvt_bf16<<<(int)(NK / 4 / 256), 256, 0, stream>>>(Wv, Wvb, (int)(NK / 4));
    cvt_bf16<<<(int)(NK / 4 / 256), 256, 0, stream>>>(Wo, Wob, (int)(NK / 4));
    rope_table<<<(SS * 64 + 255) / 256, 256, 0, stream>>>(cosT, sinT);

    dim3 gg(BB * SS / 128, HH / 128);   // (32, 16)
    gemm_bt<0><<<gg, 256, 0, stream>>>(Xb, Wqb, bq, Qb, BB * SS, HH, HH);
    gemm_bt<0><<<gg, 256, 0, stream>>>(Xb, Wkb, bk, Kb, BB * SS, HH, HH);
    gemm_bt<0><<<gg, 256, 0, stream>>>(Xb, Wvb, bv, Vb, BB * SS, HH, HH);

    int nrope = BB * SS * NHH * 64;
    rope_apply<<<nrope / 256, 256, 0, stream>>>(Qb, cosT, sinT);
    rope_apply<<<nrope / 256, 256, 0, stream>>>(Kb, cosT, sinT);

    attn_fwd<<<dim3(SS / 64, BB * NHH), 256, 0, stream>>>(Qb, Kb, Vb, AOb);

    gemm_bt<1><<<gg, 256, 0, stream>>>(AOb, Wob, bo, d_out, BB * SS, HH, HH);
}

// Round 2
// 404.944 us; speedup vs baseline: 1.3625x; 1.3625x over previous
//
#include <hip/hip_runtime.h>
#include <hip/hip_bf16.h>
#include <cstdint>
#include <cstddef>

#define BB 2
#define SS 2048
#define HH 2048
#define NHH 16
#define DHH 128

using f32x4  = __attribute__((ext_vector_type(4))) float;
using bf16x8 = __attribute__((ext_vector_type(8))) __bf16;
using bf16x4 = __attribute__((ext_vector_type(4))) __bf16;
using bfloat = __bf16;

__device__ inline void gload_lds16(const void* g, void* l) {
    __builtin_amdgcn_global_load_lds(
        (const __attribute__((address_space(1))) void*)g,
        (__attribute__((address_space(3))) void*)l, 16, 0, 0);
}

__device__ inline f32x4 mfma16(bf16x8 a, bf16x8 b, f32x4 c) {
    return __builtin_amdgcn_mfma_f32_16x16x32_bf16(a, b, c, 0, 0, 0);
}

// ---------------- fp32 -> bf16 conversion ----------------
__global__ void cvt_bf16(const float* __restrict__ in, bfloat* __restrict__ out, int n4) {
    int i = blockIdx.x * blockDim.x + threadIdx.x;
    if (i >= n4) return;
    float4 v = reinterpret_cast<const float4*>(in)[i];
    bf16x4 o;
    o[0] = (bfloat)v.x; o[1] = (bfloat)v.y; o[2] = (bfloat)v.z; o[3] = (bfloat)v.w;
    reinterpret_cast<bf16x4*>(out)[i] = o;
}

// ---------------- RoPE tables (S x 64) ----------------
__global__ void rope_table(float* __restrict__ cosT, float* __restrict__ sinT) {
    int i = blockIdx.x * blockDim.x + threadIdx.x;
    if (i >= SS * 64) return;
    int s = i >> 6, j = i & 63;
    float invf = powf(10000.0f, -(float)j / 64.0f);
    float ang = (float)s * invf;
    cosT[i] = cosf(ang);
    sinT[i] = sinf(ang);
}

// ---------------- RoPE apply in-place ----------------
__global__ void rope_apply(bfloat* __restrict__ X, const float* __restrict__ cosT,
                           const float* __restrict__ sinT) {
    int i = blockIdx.x * blockDim.x + threadIdx.x;
    if (i >= BB * SS * NHH * 64) return;
    int j = i & 63;
    int row = i >> 6;               // (b*S + s)*NH + h
    int s = (row >> 4) & (SS - 1);
    size_t base = (size_t)row * DHH;
    float x1 = (float)X[base + j];
    float x2 = (float)X[base + 64 + j];
    float c = cosT[s * 64 + j], sn = sinT[s * 64 + j];
    X[base + j]      = (bfloat)(x1 * c - x2 * sn);
    X[base + 64 + j] = (bfloat)(x2 * c + x1 * sn);
}

// ---------------- GEMM: C(MxN) = A(MxK) * Bt(NxK)^T + bias ----------------
// OUTMODE: 0 = bf16 row-major, 1 = f32 row-major, 2 = bf16 V-transposed (b,h,d,s)
template <int OUTMODE>
__global__ __launch_bounds__(256, 2)
void gemm_bt(const bfloat* __restrict__ A, const bfloat* __restrict__ Bt,
             const float* __restrict__ bias, void* __restrict__ C,
             int M, int N, int K) {
    constexpr int BM = 128, BN = 128, BK = 32;
    __shared__ bfloat As[BM * BK];
    __shared__ bfloat Bs[BN * BK];
    const int t = threadIdx.x, w = t >> 6, l = t & 63;
    const int lr = l & 15, lg = l >> 4;
    const int m0 = blockIdx.x * BM, n0 = blockIdx.y * BN;
    const int wm = (w >> 1) * 64, wn = (w & 1) * 64;
    const int base = (t & ~63) * 8;   // wave-uniform LDS element base

    f32x4 acc[4][4] = {};

    for (int kb = 0; kb < K; kb += BK) {
#pragma unroll
        for (int i = 0; i < 2; i++) {
            int idx = i * 256 + t;
            int r = idx >> 2, k8 = (idx & 3) << 3;
            gload_lds16(A  + (size_t)(m0 + r) * K + kb + k8, As + (i * 2048 + base));
            gload_lds16(Bt + (size_t)(n0 + r) * K + kb + k8, Bs + (i * 2048 + base));
        }
        __syncthreads();
        bf16x8 af[4], bfr[4];
#pragma unroll
        for (int mi = 0; mi < 4; mi++)
            af[mi] = *reinterpret_cast<const bf16x8*>(&As[(wm + mi * 16 + lr) * BK + lg * 8]);
#pragma unroll
        for (int ni = 0; ni < 4; ni++)
            bfr[ni] = *reinterpret_cast<const bf16x8*>(&Bs[(wn + ni * 16 + lr) * BK + lg * 8]);
#pragma unroll
        for (int mi = 0; mi < 4; mi++)
#pragma unroll
            for (int ni = 0; ni < 4; ni++)
                acc[mi][ni] = mfma16(af[mi], bfr[ni], acc[mi][ni]);
        __syncthreads();
    }

#pragma unroll
    for (int mi = 0; mi < 4; mi++) {
        int row = m0 + wm + mi * 16 + lg * 4;
#pragma unroll
        for (int ni = 0; ni < 4; ni++) {
            int col = n0 + wn + ni * 16 + lr;
            float bv = bias[col];
#pragma unroll
            for (int j = 0; j < 4; j++) {
                float v = acc[mi][ni][j] + bv;
                if (OUTMODE == 1) {
                    ((float*)C)[(size_t)(row + j) * N + col] = v;
                } else if (OUTMODE == 0) {
                    ((bfloat*)C)[(size_t)(row + j) * N + col] = (bfloat)v;
                } else {
                    int bb = (row + j) >> 11;           // token row -> (b, s)
                    int s  = (row + j) & (SS - 1);
                    ((bfloat*)C)[((size_t)(bb * HH + col)) * SS + s] = (bfloat)v;
                }
            }
        }
    }
}

// ---------------- Flash attention (causal), KVB=64, double-buffered ----------------
// Q,K layout: (b, s, h*DH + d).  Vt layout: (b, h, d, s).
// Block: 64 q-rows, 4 waves (16 rows each). Heavy blocks first (reversed x).
__global__ __launch_bounds__(256, 2)
void attn_fwd(const bfloat* __restrict__ Q, const bfloat* __restrict__ K,
              const bfloat* __restrict__ Vt, bfloat* __restrict__ O) {
    __shared__ bfloat Ks[2][64 * 128];   // swizzled: 16B unit u ^= (row&7)
    __shared__ bfloat Vs[2][128 * 64];   // rows = d, cols = k, swizzled
    __shared__ bfloat Pw[4][16 * 64];    // per-wave P, swizzled

    const int t = threadIdx.x, w = t >> 6, l = t & 63;
    const int lr = l & 15, lg = l >> 4;
    const int swz = (lr & 7) << 4;
    const int b = blockIdx.y >> 4, h = blockIdx.y & 15;
    const int qidx = gridDim.x - 1 - blockIdx.x;     // heavy first
    const int q0 = qidx * 64 + w * 16;
    const size_t bo_ = (size_t)b * SS * HH + (size_t)h * DHH;
    const bfloat* Qp = Q + bo_;
    const bfloat* Kp = K + bo_;
    const bfloat* Vp = Vt + (size_t)(b * NHH + h) * DHH * SS;
    bfloat* Op = O + bo_;

    // stage K tile (64 x 128) and V tile (128 d x 64 k), source pre-swizzled
    auto stage = [&](int buf, int kv0) {
#pragma unroll
        for (int i = 0; i < 4; i++) {
            int Ub = (i * 4 + w) * 64;
            int U = Ub + l;
            int r = U >> 4;
            int u = (U & 15) ^ (r & 7);
            gload_lds16(Kp + (size_t)(kv0 + r) * HH + u * 8, &Ks[buf][Ub * 8]);
        }
#pragma unroll
        for (int i = 0; i < 4; i++) {
            int Ub = (i * 4 + w) * 64;
            int U = Ub + l;
            int r = U >> 3;
            int u = (U & 7) ^ (r & 7);
            gload_lds16(Vp + (size_t)r * SS + kv0 + u * 8, &Vs[buf][Ub * 8]);
        }
    };

    // Q fragments: A[row=q0+lr][d = kt*32 + lg*8 ..]
    bf16x8 qf[4];
#pragma unroll
    for (int kt = 0; kt < 4; kt++)
        qf[kt] = *reinterpret_cast<const bf16x8*>(Qp + (size_t)(q0 + lr) * HH + kt * 32 + lg * 8);

    f32x4 o[8] = {};
    float m[4], ls[4];
#pragma unroll
    for (int j = 0; j < 4; j++) { m[j] = -1e30f; ls[j] = 0.f; }
    const float scale = 0.088388347648318447f;   // 1/sqrt(128)

    const int nkv = qidx + 1;
    stage(0, 0);
    __syncthreads();

    for (int kv = 0; kv < nkv; ++kv) {
        const int cur = kv & 1;
        if (kv + 1 < nkv) stage(cur ^ 1, (kv + 1) * 64);

        const char* KB = (const char*)&Ks[cur][0];
        const char* VB = (const char*)&Vs[cur][0];

        // QK^T: sc[kb] covers k = kv*64 + kb*16 + lr, q = q0 + lg*4 + j
        f32x4 sc[4] = {};
#pragma unroll
        for (int kt = 0; kt < 4; kt++) {
            const int col = (kt * 64 + lg * 16);
#pragma unroll
            for (int kb = 0; kb < 4; kb++) {
                bf16x8 kf = *reinterpret_cast<const bf16x8*>(
                    KB + (kb * 16 + lr) * 256 + (col ^ swz));
                sc[kb] = mfma16(qf[kt], kf, sc[kb]);
            }
        }

        const bool diag = (kv == nkv - 1);
        float p[4][4], alpha[4];
#pragma unroll
        for (int j = 0; j < 4; j++) {
            float v0 = sc[0][j] * scale, v1 = sc[1][j] * scale;
            float v2 = sc[2][j] * scale, v3 = sc[3][j] * scale;
            if (diag) {
                int qr = q0 + lg * 4 + j;
                int k0 = kv * 64 + lr;
                if (k0      > qr) v0 = -1e30f;
                if (k0 + 16 > qr) v1 = -1e30f;
                if (k0 + 32 > qr) v2 = -1e30f;
                if (k0 + 48 > qr) v3 = -1e30f;
            }
            float mx = fmaxf(fmaxf(v0, v1), fmaxf(v2, v3));
            mx = fmaxf(mx, __shfl_xor(mx, 1));
            mx = fmaxf(mx, __shfl_xor(mx, 2));
            mx = fmaxf(mx, __shfl_xor(mx, 4));
            mx = fmaxf(mx, __shfl_xor(mx, 8));
            float mn = fmaxf(m[j], mx);
            alpha[j] = __expf(m[j] - mn);
            m[j] = mn;
            p[0][j] = __expf(v0 - mn);
            p[1][j] = __expf(v1 - mn);
            p[2][j] = __expf(v2 - mn);
            p[3][j] = __expf(v3 - mn);
            float rs = (p[0][j] + p[1][j]) + (p[2][j] + p[3][j]);
            rs += __shfl_xor(rs, 1);
            rs += __shfl_xor(rs, 2);
            rs += __shfl_xor(rs, 4);
            rs += __shfl_xor(rs, 8);
            ls[j] = ls[j] * alpha[j] + rs;
        }
#pragma unroll
        for (int nt = 0; nt < 8; nt++)
#pragma unroll
            for (int j = 0; j < 4; j++) o[nt][j] *= alpha[j];

        // write P (wave-private, swizzled): row q = lg*4+j, col k = kb*16 + lr
        char* pwb = (char*)&Pw[w][0];
#pragma unroll
        for (int j = 0; j < 4; j++) {
            int q = lg * 4 + j;
            int qs = (q & 7) << 4;
#pragma unroll
            for (int kb = 0; kb < 4; kb++)
                *(bfloat*)(pwb + q * 128 + ((kb * 32 + lr * 2) ^ qs)) = (bfloat)p[kb][j];
        }
        asm volatile("s_waitcnt lgkmcnt(0)" ::: "memory");
        __builtin_amdgcn_sched_barrier(0);

        // PV: A = P[q=lr][k], B = V[k][d=nt*16+lr]
        const char* pwr = (const char*)&Pw[w][0];
        bf16x8 pa0 = *reinterpret_cast<const bf16x8*>(pwr + lr * 128 + ((lg * 16) ^ swz));
        bf16x8 pa1 = *reinterpret_cast<const bf16x8*>(pwr + lr * 128 + ((64 + lg * 16) ^ swz));
#pragma unroll
        for (int nt = 0; nt < 8; nt++) {
            const char* vb = VB + (nt * 16 + lr) * 128;
            bf16x8 vf0 = *reinterpret_cast<const bf16x8*>(vb + ((lg * 16) ^ swz));
            bf16x8 vf1 = *reinterpret_cast<const bf16x8*>(vb + ((64 + lg * 16) ^ swz));
            o[nt] = mfma16(pa0, vf0, o[nt]);
            o[nt] = mfma16(pa1, vf1, o[nt]);
        }
        __syncthreads();
    }

#pragma unroll
    for (int j = 0; j < 4; j++) {
        float inv = 1.0f / ls[j];
        int row = q0 + lg * 4 + j;
#pragma unroll
        for (int nt = 0; nt < 8; nt++)
            Op[(size_t)row * HH + nt * 16 + lr] = (bfloat)(o[nt][j] * inv);
    }
}

// ---------------- launch ----------------
extern "C" void kernel_launch(void* const* d_in, const int* in_sizes, int n_in,
                              void* d_out, int out_size, void* d_ws, size_t ws_size,
                              hipStream_t stream) {
    (void)in_sizes; (void)n_in; (void)out_size; (void)ws_size;
    const float* hs = (const float*)d_in[0];
    const float* Wq = (const float*)d_in[2];
    const float* bq = (const float*)d_in[3];
    const float* Wk = (const float*)d_in[4];
    const float* bk = (const float*)d_in[5];
    const float* Wv = (const float*)d_in[6];
    const float* bv = (const float*)d_in[7];
    const float* Wo = (const float*)d_in[8];
    const float* bo = (const float*)d_in[9];

    char* ws = (char*)d_ws;
    size_t off = 0;
    auto alloc = [&](size_t bytes) { void* p = ws + off; off += (bytes + 255) & ~(size_t)255; return p; };
    const size_t MK = (size_t)BB * SS * HH;   // 8M elems
    const size_t NK = (size_t)HH * HH;        // 4M elems

    bfloat* Xb  = (bfloat*)alloc(MK * 2);
    bfloat* Wqb = (bfloat*)alloc(NK * 2);
    bfloat* Wkb = (bfloat*)alloc(NK * 2);
    bfloat* Wvb = (bfloat*)alloc(NK * 2);
    bfloat* Wob = (bfloat*)alloc(NK * 2);
    bfloat* Qb  = (bfloat*)alloc(MK * 2);
    bfloat* Kb  = (bfloat*)alloc(MK * 2);
    bfloat* Vtb = (bfloat*)alloc(MK * 2);     // (b, h, d, s)
    float*  cosT = (float*)alloc((size_t)SS * 64 * 4);
    float*  sinT = (float*)alloc((size_t)SS * 64 * 4);
    bfloat* AOb = Xb;   // reuse: X no longer needed after V GEMM

    cvt_bf16<<<(int)(MK / 4 / 256), 256, 0, stream>>>(hs, Xb, (int)(MK / 4));
    cvt_bf16<<<(int)(NK / 4 / 256), 256, 0, stream>>>(Wq, Wqb, (int)(NK / 4));
    cvt_bf16<<<(int)(NK / 4 / 256), 256, 0, stream>>>(Wk, Wkb, (int)(NK / 4));
    cvt_bf16<<<(int)(NK / 4 / 256), 256, 0, stream>>>(Wv, Wvb, (int)(NK / 4));
    cvt_bf16<<<(int)(NK / 4 / 256), 256, 0, stream>>>(Wo, Wob, (int)(NK / 4));
    rope_table<<<(SS * 64 + 255) / 256, 256, 0, stream>>>(cosT, sinT);

    dim3 gg(BB * SS / 128, HH / 128);   // (32, 16)
    gemm_bt<0><<<gg, 256, 0, stream>>>(Xb, Wqb, bq, Qb, BB * SS, HH, HH);
    gemm_bt<0><<<gg, 256, 0, stream>>>(Xb, Wkb, bk, Kb, BB * SS, HH, HH);
    gemm_bt<2><<<gg, 256, 0, stream>>>(Xb, Wvb, bv, Vtb, BB * SS, HH, HH);

    int nrope = BB * SS * NHH * 64;
    rope_apply<<<nrope / 256, 256, 0, stream>>>(Qb, cosT, sinT);
    rope_apply<<<nrope / 256, 256, 0, stream>>>(Kb, cosT, sinT);

    attn_fwd<<<dim3(SS / 64, BB * NHH), 256, 0, stream>>>(Qb, Kb, Vtb, AOb);

    gemm_bt<1><<<gg, 256, 0, stream>>>(AOb, Wob, bo, d_out, BB * SS, HH, HH);
}